// Round 5
// baseline (462.846 us; speedup 1.0000x reference)
//
#include <hip/hip_runtime.h>
#include <cstdint>
#include <math.h>

#define DIMC 192
#define NTOK 256
#define HEADS 6
#define HD 32
#define L2E 1.4426950408889634f

typedef __bf16 bf16x8 __attribute__((ext_vector_type(8)));
typedef __bf16 bf16x4 __attribute__((ext_vector_type(4)));
typedef float f32x4 __attribute__((ext_vector_type(4)));

__device__ __forceinline__ void gload_lds16(const __bf16* g, __bf16* l) {
    __builtin_amdgcn_global_load_lds((const __attribute__((address_space(1))) void*)g,
                                     (__attribute__((address_space(3))) void*)l, 16, 0, 0);
}

// ---------------- fused prep: cast_x | transcast(qkv_w) | transcast(proj_w) | biasb ----------------
// biasb is pre-multiplied by log2(e) so attention can use v_exp_f32 (base-2) directly.
__global__ void prep(const float* __restrict__ x, __bf16* __restrict__ xb,
                     const float* __restrict__ qkv_w, __bf16* __restrict__ wqt,
                     const float* __restrict__ proj_w, __bf16* __restrict__ wpt,
                     const float* __restrict__ table, const int* __restrict__ rel,
                     __bf16* __restrict__ biasb) {
    const int bid = blockIdx.x, t = threadIdx.x;
    if (bid < 6144) {                               // cast x -> bf16, one bf16x8/thread
        int i = bid * 256 + t;
        float4 a = ((const float4*)x)[i * 2];
        float4 b = ((const float4*)x)[i * 2 + 1];
        bf16x8 o = {(__bf16)a.x, (__bf16)a.y, (__bf16)a.z, (__bf16)a.w,
                    (__bf16)b.x, (__bf16)b.y, (__bf16)b.z, (__bf16)b.w};
        ((bf16x8*)xb)[i] = o;
    } else if (bid < 6576) {                        // wqt[n][k] = qkv_w[k][n]
        int i = (bid - 6144) * 256 + t;             // i < 576*192
        int n = i / DIMC, k = i - n * DIMC;
        wqt[i] = (__bf16)qkv_w[(size_t)k * 576 + n];
    } else if (bid < 6720) {                        // wpt[n][k] = proj_w[k][n]
        int i = (bid - 6576) * 256 + t;             // i < 192*192
        int n = i / DIMC, k = i - n * DIMC;
        wpt[i] = (__bf16)proj_w[(size_t)k * DIMC + n];
    } else {                                        // biasb[h][q][k] = bf16(table[rel]*log2e)
        int i = (bid - 6720) * 256 + t;             // i < 6*65536
        int h = i >> 16;
        int r = i & 65535;
        biasb[i] = (__bf16)(table[rel[r] * 6 + h] * L2E);
    }
}

// ---------------- fused QKV GEMM + bm build ----------------
// blocks [0,1536): MFMA GEMM (65536x192)x(192x576), XCD-aware remap.
//   q scaled by 1/sqrt(hd)*log2e; V written TRANSPOSED as vT[b,h,d,n] (attn consumes V^T only).
// blocks [1536,3584): bm[w][h][q][k] = bf16(mask*log2e + biasb)  (pure-BW, overlaps GEMM tail)
__launch_bounds__(256, 2)
__global__ void qkvbm(const __bf16* __restrict__ A, const __bf16* __restrict__ Wt,
                      const float* __restrict__ bias,
                      __bf16* __restrict__ qo, __bf16* __restrict__ ko, __bf16* __restrict__ vo,
                      const float* __restrict__ mask, const __bf16* __restrict__ biasb,
                      __bf16* __restrict__ bm) {
    __shared__ __bf16 As[256 * 64];    // 32KB
    __shared__ __bf16 Bs[96 * 64];     // 12KB
    const int t = threadIdx.x;
    const int lin = blockIdx.x;

    if (lin >= 1536) {                              // ---- bm build ----
        int i = (lin - 1536) * 256 + t;             // i < 64*8192
        int w = i >> 13, oct = i & 8191;
        float4 m0 = ((const float4*)mask)[(size_t)w * 16384 + oct * 2];
        float4 m1 = ((const float4*)mask)[(size_t)w * 16384 + oct * 2 + 1];
        #pragma unroll
        for (int h = 0; h < 6; ++h) {
            bf16x8 bb = ((const bf16x8*)biasb)[h * 8192 + oct];
            bf16x8 o = {(__bf16)(m0.x * L2E + (float)bb[0]), (__bf16)(m0.y * L2E + (float)bb[1]),
                        (__bf16)(m0.z * L2E + (float)bb[2]), (__bf16)(m0.w * L2E + (float)bb[3]),
                        (__bf16)(m1.x * L2E + (float)bb[4]), (__bf16)(m1.y * L2E + (float)bb[5]),
                        (__bf16)(m1.z * L2E + (float)bb[6]), (__bf16)(m1.w * L2E + (float)bb[7])};
            ((bf16x8*)bm)[(size_t)(w * 6 + h) * 8192 + oct] = o;
        }
        return;
    }

    const int wv = t >> 6, lane = t & 63;
    const int l16 = lane & 15, quad = lane >> 4;
    const int xcd = lin & 7, pos = lin >> 3;        // pos < 192
    const int bx = pos % 6;                         // column block (96 cols)
    const int by = xcd + (pos / 6) * 8;             // row block [0,256)
    const int m0 = by * 256;
    const int j0 = bx * 96;

    f32x4 acc[4][6];
    #pragma unroll
    for (int mt = 0; mt < 4; ++mt)
        #pragma unroll
        for (int nt = 0; nt < 6; ++nt)
            acc[mt][nt] = (f32x4){0.f, 0.f, 0.f, 0.f};

    for (int kit = 0; kit < 3; ++kit) {
        const int k0 = kit * 64;
        #pragma unroll
        for (int gi = 0; gi < 8; ++gi) {            // A: 2048 chunks, 32 groups
            int g = wv * 8 + gi;
            int cid = g * 64 + lane;
            int row = cid >> 3, kcs = cid & 7;
            int kcg = kcs ^ (row & 7);
            gload_lds16(A + (size_t)(m0 + row) * DIMC + k0 + kcg * 8, As + g * 512);
        }
        #pragma unroll
        for (int gi = 0; gi < 3; ++gi) {            // B: 768 chunks, 12 groups
            int g = wv * 3 + gi;
            int cid = g * 64 + lane;
            int n = cid >> 3, kcs = cid & 7;
            int kcg = kcs ^ (n & 7);
            gload_lds16(Wt + (size_t)(j0 + n) * DIMC + k0 + kcg * 8, Bs + g * 512);
        }
        __syncthreads();
        #pragma unroll
        for (int kk = 0; kk < 2; ++kk) {
            bf16x8 af[4], bfr[6];
            #pragma unroll
            for (int mt = 0; mt < 4; ++mt) {
                int row = wv * 64 + mt * 16 + l16;
                int ch = (kk * 4 + quad) ^ (row & 7);
                af[mt] = *(const bf16x8*)(As + row * 64 + ch * 8);
            }
            #pragma unroll
            for (int nt = 0; nt < 6; ++nt) {
                int n = nt * 16 + l16;
                int ch = (kk * 4 + quad) ^ (n & 7);
                bfr[nt] = *(const bf16x8*)(Bs + n * 64 + ch * 8);
            }
            #pragma unroll
            for (int mt = 0; mt < 4; ++mt)
                #pragma unroll
                for (int nt = 0; nt < 6; ++nt)
                    acc[mt][nt] = __builtin_amdgcn_mfma_f32_16x16x32_bf16(af[mt], bfr[nt], acc[mt][nt], 0, 0, 0);
        }
        __syncthreads();
    }

    const int which = bx >> 1;                      // 0=q, 1=k, 2=v
    __bf16* outp = which == 0 ? qo : (which == 1 ? ko : vo);
    const float sc = which == 0 ? (0.17677669529663687f * L2E) : 1.0f;
    float bq[6];
    #pragma unroll
    for (int nt = 0; nt < 6; ++nt) bq[nt] = bias[j0 + nt * 16 + l16];
    const int cloc = (bx & 1) * 96;                 // col within 192
    const int b = m0 >> 8;                          // batch (m0 is a multiple of 256)

    if (which != 2) {
        // q/k epilogue: re-tile via per-wave LDS, write bf16 [b,h,n,d] with 16B stores
        __bf16* tile = As + wv * 4096;              // per-wave 8KB, [16][104]
        const int TP = 104;
        #pragma unroll
        for (int mt = 0; mt < 4; ++mt) {
            #pragma unroll
            for (int nt = 0; nt < 6; ++nt)
                #pragma unroll
                for (int r = 0; r < 4; ++r)
                    tile[(quad * 4 + r) * TP + nt * 16 + l16] = (__bf16)((acc[mt][nt][r] + bq[nt]) * sc);
            int row = lane >> 2;
            #pragma unroll
            for (int it = 0; it < 3; ++it) {
                int c8 = (lane & 3) + it * 4;       // 12 16B-chunks per row
                bf16x8 val = *(const bf16x8*)(tile + row * TP + c8 * 8);
                int n = wv * 64 + mt * 16 + row;
                int cw = cloc + c8 * 8;
                int h = cw >> 5, d0 = cw & 31;
                *(bf16x8*)(outp + (((size_t)b * HEADS + h) * NTOK + n) * HD + d0) = val;
            }
        }
    } else {
        // v epilogue: transposed store vT[b,h,d,n] via per-wave LDS tileT[96][16]
        __bf16* tileT = As + wv * 4096;             // per-wave, 96*16 bf16 = 3KB
        #pragma unroll
        for (int mt = 0; mt < 4; ++mt) {
            #pragma unroll
            for (int nt = 0; nt < 6; ++nt)
                #pragma unroll
                for (int r = 0; r < 4; ++r)
                    tileT[(nt * 16 + l16) * 16 + quad * 4 + r] = (__bf16)(acc[mt][nt][r] + bq[nt]);
            int n0 = wv * 64 + mt * 16;
            #pragma unroll
            for (int it = 0; it < 3; ++it) {
                int qid = lane + 64 * it;           // < 192
                int col = qid >> 1, half = qid & 1;
                bf16x8 val = *(const bf16x8*)(tileT + col * 16 + half * 8);
                int cw = cloc + col;
                int h = cw >> 5, d = cw & 31;
                *(bf16x8*)(outp + (((size_t)b * HEADS + h) * HD + d) * NTOK + n0 + half * 8) = val;
            }
        }
    }
}

// ---------------- MFMA attention: in-register P via permuted-K rows ----------------
// K fragment rows loaded in permuted order kappa(kt,p)=8*(p>>2)+(p&3)+4*kt, so QK^T's
// output lands with lane (quad,l16) holding keys 8*quad..8*quad+7 for query l16 ==
// exactly the PV A-fragment. P never touches LDS; qt iterations fully independent.
// Ks swizzle G(key)=bit1|bit3<<1 keeps the permuted read 2-way (free) in banks.
// LDS = 16K (K) + 16K (V^T) = 32768 B -> 5 blocks/CU.
__launch_bounds__(256, 5)
__global__ void attn_mfma(const __bf16* __restrict__ qg, const __bf16* __restrict__ kg,
                          const __bf16* __restrict__ vtg, const __bf16* __restrict__ bm,
                          __bf16* __restrict__ aout) {
    __shared__ __bf16 Ks[NTOK * 32];    // [key][dim], chunk c stores K[key][c ^ G(key)]
    __shared__ __bf16 VTs[HD * 256];    // [d][n],    chunk c stores vT[d][c ^ (d&7)]

    const int lin = blockIdx.x;                     // [0,1536)
    const int xcd = lin & 7, pos = lin >> 3;        // pos < 192
    const int g = xcd + (pos >> 2) * 8;             // (w,h) group [0,384)
    const int i4 = pos & 3;                         // batch group [0,4)
    const int h = g % 6, w = g / 6;
    const int b = i4 * 64 + w;
    const int bh = b * HEADS + h;

    const int t = threadIdx.x;
    const int wv = t >> 6, lane = t & 63;
    const int l16 = lane & 15, quad = lane >> 4;
    const int q0 = wv * 64;
    const size_t base = (size_t)bh * (NTOK * HD);

    #pragma unroll
    for (int it = 0; it < 4; ++it) {                // K: 1024 chunks, G-swizzled source
        int grp = it * 4 + wv;
        int cid = grp * 64 + lane;
        int row = cid >> 2, cc = cid & 3;
        int scc = cc ^ (((row >> 1) & 1) | (((row >> 3) & 1) << 1));
        gload_lds16(kg + base + row * HD + scc * 8, Ks + grp * 512);
    }
    #pragma unroll
    for (int it = 0; it < 4; ++it) {                // V^T: 1024 chunks, swizzled source
        int grp = it * 4 + wv;
        int cid = grp * 64 + lane;
        int row = cid >> 5, cc = cid & 31;
        int scc = cc ^ (row & 7);
        gload_lds16(vtg + base + row * NTOK + scc * 8, VTs + grp * 512);
    }
    __syncthreads();

    bf16x8 qf[4];
    #pragma unroll
    for (int qt = 0; qt < 4; ++qt)
        qf[qt] = *(const bf16x8*)(qg + base + (size_t)(q0 + qt * 16 + l16) * HD + quad * 8);

    f32x4 o[4][2];
    #pragma unroll
    for (int qt = 0; qt < 4; ++qt)
        #pragma unroll
        for (int dt = 0; dt < 2; ++dt)
            o[qt][dt] = (f32x4){0.f, 0.f, 0.f, 0.f};
    float rsum[4] = {};

    // bm: with the key permutation, lane (quad,l16) needs keys kb+8*quad..+8 -> ONE bf16x8
    const __bf16* bmq = bm + (size_t)(w * 6 + h) * 65536 + (size_t)(q0 + l16) * 256 + quad * 8;
    // permuted K-row index within the 32-key block, and its bank-fix read chunk
    const int kapb = 8 * (l16 >> 2) + (l16 & 3);    // kappa = kapb + 4*kt
    const int ck = quad ^ ((l16 >> 1) & 1) ^ (((l16 >> 2) & 1) << 1);
    const int xv = l16 & 7;                         // V read chunk XOR

    // prologue: prefetch bm for c=0
    bf16x8 bmv[4];
    #pragma unroll
    for (int qt = 0; qt < 4; ++qt)
        bmv[qt] = *(const bf16x8*)(bmq + qt * 4096);

    for (int c = 0; c < 8; ++c) {
        const int kb = c * 32;
        bf16x8 bmn[4];
        if (c < 7) {                                 // issue next tile's bm loads early
            #pragma unroll
            for (int qt = 0; qt < 4; ++qt)
                bmn[qt] = *(const bf16x8*)(bmq + qt * 4096 + kb + 32);
        }
        bf16x8 kf[2];
        #pragma unroll
        for (int kt = 0; kt < 2; ++kt)
            kf[kt] = *(const bf16x8*)(Ks + (kb + kapb + 4 * kt) * 32 + ck * 8);
        bf16x8 vf[2];
        #pragma unroll
        for (int dt = 0; dt < 2; ++dt) {
            int cv = (c * 4 + quad) ^ xv;
            vf[dt] = *(const bf16x8*)(VTs + (dt * 16 + l16) * 256 + cv * 8);
        }

        #pragma unroll
        for (int qt = 0; qt < 4; ++qt) {
            bf16x8 pf;
            #pragma unroll
            for (int kt = 0; kt < 2; ++kt) {
                f32x4 s = (f32x4){0.f, 0.f, 0.f, 0.f};
                s = __builtin_amdgcn_mfma_f32_16x16x32_bf16(kf[kt], qf[qt], s, 0, 0, 0);
                #pragma unroll
                for (int r = 0; r < 4; ++r) {
                    float p = __builtin_amdgcn_exp2f(s[r] + (float)bmv[qt][kt * 4 + r]);
                    rsum[qt] += p;
                    pf[kt * 4 + r] = (__bf16)p;
                }
            }
            #pragma unroll
            for (int dt = 0; dt < 2; ++dt)
                o[qt][dt] = __builtin_amdgcn_mfma_f32_16x16x32_bf16(pf, vf[dt], o[qt][dt], 0, 0, 0);
        }
        if (c < 7) {
            #pragma unroll
            for (int qt = 0; qt < 4; ++qt)
                bmv[qt] = bmn[qt];
        }
    }

    // row-sum reciprocal broadcast via shfl (no LDS, no divergence)
    float rstot[4];
    #pragma unroll
    for (int qt = 0; qt < 4; ++qt) {
        float s = rsum[qt];
        s += __shfl_xor(s, 16);
        s += __shfl_xor(s, 32);
        rstot[qt] = 1.0f / s;
    }
    #pragma unroll
    for (int qt = 0; qt < 4; ++qt) {
        #pragma unroll
        for (int r = 0; r < 4; ++r) {
            float inv = __shfl(rstot[qt], (lane & 48) | (quad * 4 + r));
            int qrow = q0 + qt * 16 + quad * 4 + r;
            #pragma unroll
            for (int dt = 0; dt < 2; ++dt)
                aout[((size_t)b * NTOK + qrow) * DIMC + h * HD + dt * 16 + l16] =
                    (__bf16)(o[qt][dt][r] * inv);
        }
    }
}

// ---------------- proj GEMM via MFMA: (65536x192)x(192x192) + bias, fp32 out ----------------
__launch_bounds__(256, 2)
__global__ void proj_mfma(const __bf16* __restrict__ A, const __bf16* __restrict__ Wt,
                          const float* __restrict__ bias, float* __restrict__ out) {
    __shared__ __bf16 As[256 * 64];
    __shared__ __bf16 Bs[96 * 64];
    const int t = threadIdx.x;
    const int wv = t >> 6, lane = t & 63;
    const int l16 = lane & 15, quad = lane >> 4;

    const int lin = blockIdx.x + blockIdx.y * 2;    // [0,512)
    const int xcd = lin & 7, pos = lin >> 3;        // pos < 64
    const int bx = pos & 1;
    const int by = xcd + (pos >> 1) * 8;            // [0,256)

    const int m0 = by * 256;
    const int j0 = bx * 96;

    f32x4 acc[4][6];
    #pragma unroll
    for (int mt = 0; mt < 4; ++mt)
        #pragma unroll
        for (int nt = 0; nt < 6; ++nt)
            acc[mt][nt] = (f32x4){0.f, 0.f, 0.f, 0.f};

    for (int kit = 0; kit < 3; ++kit) {
        const int k0 = kit * 64;
        #pragma unroll
        for (int gi = 0; gi < 8; ++gi) {
            int g = wv * 8 + gi;
            int cid = g * 64 + lane;
            int row = cid >> 3, kcs = cid & 7;
            int kcg = kcs ^ (row & 7);
            gload_lds16(A + (size_t)(m0 + row) * DIMC + k0 + kcg * 8, As + g * 512);
        }
        #pragma unroll
        for (int gi = 0; gi < 3; ++gi) {
            int g = wv * 3 + gi;
            int cid = g * 64 + lane;
            int n = cid >> 3, kcs = cid & 7;
            int kcg = kcs ^ (n & 7);
            gload_lds16(Wt + (size_t)(j0 + n) * DIMC + k0 + kcg * 8, Bs + g * 512);
        }
        __syncthreads();
        #pragma unroll
        for (int kk = 0; kk < 2; ++kk) {
            bf16x8 af[4], bfr[6];
            #pragma unroll
            for (int mt = 0; mt < 4; ++mt) {
                int row = wv * 64 + mt * 16 + l16;
                int ch = (kk * 4 + quad) ^ (row & 7);
                af[mt] = *(const bf16x8*)(As + row * 64 + ch * 8);
            }
            #pragma unroll
            for (int nt = 0; nt < 6; ++nt) {
                int n = nt * 16 + l16;
                int ch = (kk * 4 + quad) ^ (n & 7);
                bfr[nt] = *(const bf16x8*)(Bs + n * 64 + ch * 8);
            }
            #pragma unroll
            for (int mt = 0; mt < 4; ++mt)
                #pragma unroll
                for (int nt = 0; nt < 6; ++nt)
                    acc[mt][nt] = __builtin_amdgcn_mfma_f32_16x16x32_bf16(af[mt], bfr[nt], acc[mt][nt], 0, 0, 0);
        }
        __syncthreads();
    }

    #pragma unroll
    for (int nt = 0; nt < 6; ++nt) {
        int colg = j0 + nt * 16 + l16;
        float bv = bias[colg];
        #pragma unroll
        for (int mt = 0; mt < 4; ++mt)
            #pragma unroll
            for (int r = 0; r < 4; ++r) {
                int token = m0 + wv * 64 + mt * 16 + quad * 4 + r;
                out[(size_t)token * DIMC + colg] = acc[mt][nt][r] + bv;
            }
    }
}

extern "C" void kernel_launch(void* const* d_in, const int* in_sizes, int n_in,
                              void* d_out, int out_size, void* d_ws, size_t ws_size,
                              hipStream_t stream) {
    const float* x          = (const float*)d_in[0];
    const float* mask       = (const float*)d_in[1];
    const float* qkv_w      = (const float*)d_in[2];
    const float* qkv_b      = (const float*)d_in[3];
    const float* proj_w     = (const float*)d_in[4];
    const float* proj_b     = (const float*)d_in[5];
    const float* bias_table = (const float*)d_in[6];
    const int*   rel_index  = (const int*)d_in[7];

    char* ws = (char*)d_ws;
    __bf16* xb    = (__bf16*)(ws);                  // 25,165,824 B (reused as aoutb)
    __bf16* q     = (__bf16*)(ws + 25165824);
    __bf16* k     = (__bf16*)(ws + 50331648);
    __bf16* vT    = (__bf16*)(ws + 75497472);       // V stored transposed [b,h,d,n]
    __bf16* biasb = (__bf16*)(ws + 100663296);      // 786,432 B (bf16 bias planes, *log2e)
    __bf16* wqt   = (__bf16*)(ws + 102236160);      // 221,184 B
    __bf16* wpt   = (__bf16*)(ws + 102457344);      // 73,728 B -> total ~102.5 MB
    __bf16* aoutb = xb;                             // xb dead after qkvbm
    __bf16* bm    = (__bf16*)d_out;                 // 50,331,648 B == out_size; d_out dead
                                                    // until proj_mfma overwrites it fully

    prep<<<8256, 256, 0, stream>>>(x, xb, qkv_w, wqt, proj_w, wpt, bias_table, rel_index, biasb);
    qkvbm<<<3584, 256, 0, stream>>>(xb, wqt, qkv_b, q, k, vT, mask, biasb, bm);
    attn_mfma<<<1536, 256, 0, stream>>>(q, k, vT, bm, aoutb);
    proj_mfma<<<dim3(2, 256), 256, 0, stream>>>(aoutb, wpt, proj_b, (float*)d_out);
}

// Round 6
// 211.711 us; speedup vs baseline: 2.1862x; 2.1862x over previous
//
#include <hip/hip_runtime.h>
#include <cstdint>
#include <math.h>

#define DIMC 192
#define NTOK 256
#define HEADS 6
#define HD 32
#define L2E 1.4426950408889634f

typedef __bf16 bf16x8 __attribute__((ext_vector_type(8)));
typedef __bf16 bf16x4 __attribute__((ext_vector_type(4)));
typedef float f32x4 __attribute__((ext_vector_type(4)));

__device__ __forceinline__ void gload_lds16(const __bf16* g, __bf16* l) {
    __builtin_amdgcn_global_load_lds((const __attribute__((address_space(1))) void*)g,
                                     (__attribute__((address_space(3))) void*)l, 16, 0, 0);
}

// ---------------- fused prep: cast_x | transcast(qkv_w) | transcast(proj_w) | biasb ----------------
// biasb is pre-multiplied by log2(e) so attention can use v_exp_f32 (base-2) directly.
__global__ void prep(const float* __restrict__ x, __bf16* __restrict__ xb,
                     const float* __restrict__ qkv_w, __bf16* __restrict__ wqt,
                     const float* __restrict__ proj_w, __bf16* __restrict__ wpt,
                     const float* __restrict__ table, const int* __restrict__ rel,
                     __bf16* __restrict__ biasb) {
    const int bid = blockIdx.x, t = threadIdx.x;
    if (bid < 6144) {                               // cast x -> bf16, one bf16x8/thread
        int i = bid * 256 + t;
        float4 a = ((const float4*)x)[i * 2];
        float4 b = ((const float4*)x)[i * 2 + 1];
        bf16x8 o = {(__bf16)a.x, (__bf16)a.y, (__bf16)a.z, (__bf16)a.w,
                    (__bf16)b.x, (__bf16)b.y, (__bf16)b.z, (__bf16)b.w};
        ((bf16x8*)xb)[i] = o;
    } else if (bid < 6576) {                        // wqt[n][k] = qkv_w[k][n]
        int i = (bid - 6144) * 256 + t;             // i < 576*192
        int n = i / DIMC, k = i - n * DIMC;
        wqt[i] = (__bf16)qkv_w[(size_t)k * 576 + n];
    } else if (bid < 6720) {                        // wpt[n][k] = proj_w[k][n]
        int i = (bid - 6576) * 256 + t;             // i < 192*192
        int n = i / DIMC, k = i - n * DIMC;
        wpt[i] = (__bf16)proj_w[(size_t)k * DIMC + n];
    } else {                                        // biasb[h][q][k] = bf16(table[rel]*log2e)
        int i = (bid - 6720) * 256 + t;             // i < 6*65536
        int h = i >> 16;
        int r = i & 65535;
        biasb[i] = (__bf16)(table[rel[r] * 6 + h] * L2E);
    }
}

// ---------------- fused QKV GEMM + bm build ----------------
// blocks [0,1536): MFMA GEMM (65536x192)x(192x576), XCD-aware remap.
//   q scaled by 1/sqrt(hd)*log2e; V written TRANSPOSED as vT[b,h,d,n] (attn consumes V^T only).
// blocks [1536,3584): bm[w][h][q][k] = bf16(mask*log2e + biasb)  (pure-BW, overlaps GEMM tail)
__launch_bounds__(256, 2)
__global__ void qkvbm(const __bf16* __restrict__ A, const __bf16* __restrict__ Wt,
                      const float* __restrict__ bias,
                      __bf16* __restrict__ qo, __bf16* __restrict__ ko, __bf16* __restrict__ vo,
                      const float* __restrict__ mask, const __bf16* __restrict__ biasb,
                      __bf16* __restrict__ bm) {
    __shared__ __bf16 As[256 * 64];    // 32KB
    __shared__ __bf16 Bs[96 * 64];     // 12KB
    const int t = threadIdx.x;
    const int lin = blockIdx.x;

    if (lin >= 1536) {                              // ---- bm build ----
        int i = (lin - 1536) * 256 + t;             // i < 64*8192
        int w = i >> 13, oct = i & 8191;
        float4 m0 = ((const float4*)mask)[(size_t)w * 16384 + oct * 2];
        float4 m1 = ((const float4*)mask)[(size_t)w * 16384 + oct * 2 + 1];
        #pragma unroll
        for (int h = 0; h < 6; ++h) {
            bf16x8 bb = ((const bf16x8*)biasb)[h * 8192 + oct];
            bf16x8 o = {(__bf16)(m0.x * L2E + (float)bb[0]), (__bf16)(m0.y * L2E + (float)bb[1]),
                        (__bf16)(m0.z * L2E + (float)bb[2]), (__bf16)(m0.w * L2E + (float)bb[3]),
                        (__bf16)(m1.x * L2E + (float)bb[4]), (__bf16)(m1.y * L2E + (float)bb[5]),
                        (__bf16)(m1.z * L2E + (float)bb[6]), (__bf16)(m1.w * L2E + (float)bb[7])};
            ((bf16x8*)bm)[(size_t)(w * 6 + h) * 8192 + oct] = o;
        }
        return;
    }

    const int wv = t >> 6, lane = t & 63;
    const int l16 = lane & 15, quad = lane >> 4;
    const int xcd = lin & 7, pos = lin >> 3;        // pos < 192
    const int bx = pos % 6;                         // column block (96 cols)
    const int by = xcd + (pos / 6) * 8;             // row block [0,256)
    const int m0 = by * 256;
    const int j0 = bx * 96;

    f32x4 acc[4][6];
    #pragma unroll
    for (int mt = 0; mt < 4; ++mt)
        #pragma unroll
        for (int nt = 0; nt < 6; ++nt)
            acc[mt][nt] = (f32x4){0.f, 0.f, 0.f, 0.f};

    for (int kit = 0; kit < 3; ++kit) {
        const int k0 = kit * 64;
        #pragma unroll
        for (int gi = 0; gi < 8; ++gi) {            // A: 2048 chunks, 32 groups
            int g = wv * 8 + gi;
            int cid = g * 64 + lane;
            int row = cid >> 3, kcs = cid & 7;
            int kcg = kcs ^ (row & 7);
            gload_lds16(A + (size_t)(m0 + row) * DIMC + k0 + kcg * 8, As + g * 512);
        }
        #pragma unroll
        for (int gi = 0; gi < 3; ++gi) {            // B: 768 chunks, 12 groups
            int g = wv * 3 + gi;
            int cid = g * 64 + lane;
            int n = cid >> 3, kcs = cid & 7;
            int kcg = kcs ^ (n & 7);
            gload_lds16(Wt + (size_t)(j0 + n) * DIMC + k0 + kcg * 8, Bs + g * 512);
        }
        __syncthreads();
        #pragma unroll
        for (int kk = 0; kk < 2; ++kk) {
            bf16x8 af[4], bfr[6];
            #pragma unroll
            for (int mt = 0; mt < 4; ++mt) {
                int row = wv * 64 + mt * 16 + l16;
                int ch = (kk * 4 + quad) ^ (row & 7);
                af[mt] = *(const bf16x8*)(As + row * 64 + ch * 8);
            }
            #pragma unroll
            for (int nt = 0; nt < 6; ++nt) {
                int n = nt * 16 + l16;
                int ch = (kk * 4 + quad) ^ (n & 7);
                bfr[nt] = *(const bf16x8*)(Bs + n * 64 + ch * 8);
            }
            #pragma unroll
            for (int mt = 0; mt < 4; ++mt)
                #pragma unroll
                for (int nt = 0; nt < 6; ++nt)
                    acc[mt][nt] = __builtin_amdgcn_mfma_f32_16x16x32_bf16(af[mt], bfr[nt], acc[mt][nt], 0, 0, 0);
        }
        __syncthreads();
    }

    const int which = bx >> 1;                      // 0=q, 1=k, 2=v
    __bf16* outp = which == 0 ? qo : (which == 1 ? ko : vo);
    const float sc = which == 0 ? (0.17677669529663687f * L2E) : 1.0f;
    float bq[6];
    #pragma unroll
    for (int nt = 0; nt < 6; ++nt) bq[nt] = bias[j0 + nt * 16 + l16];
    const int cloc = (bx & 1) * 96;                 // col within 192
    const int b = m0 >> 8;                          // batch (m0 is a multiple of 256)

    if (which != 2) {
        // q/k epilogue: re-tile via per-wave LDS, write bf16 [b,h,n,d] with 16B stores
        __bf16* tile = As + wv * 4096;              // per-wave 8KB, [16][104]
        const int TP = 104;
        #pragma unroll
        for (int mt = 0; mt < 4; ++mt) {
            #pragma unroll
            for (int nt = 0; nt < 6; ++nt)
                #pragma unroll
                for (int r = 0; r < 4; ++r)
                    tile[(quad * 4 + r) * TP + nt * 16 + l16] = (__bf16)((acc[mt][nt][r] + bq[nt]) * sc);
            int row = lane >> 2;
            #pragma unroll
            for (int it = 0; it < 3; ++it) {
                int c8 = (lane & 3) + it * 4;       // 12 16B-chunks per row
                bf16x8 val = *(const bf16x8*)(tile + row * TP + c8 * 8);
                int n = wv * 64 + mt * 16 + row;
                int cw = cloc + c8 * 8;
                int h = cw >> 5, d0 = cw & 31;
                *(bf16x8*)(outp + (((size_t)b * HEADS + h) * NTOK + n) * HD + d0) = val;
            }
        }
    } else {
        // v epilogue: transposed store vT[b,h,d,n] via per-wave LDS tileT[96][16]
        __bf16* tileT = As + wv * 4096;             // per-wave, 96*16 bf16 = 3KB
        #pragma unroll
        for (int mt = 0; mt < 4; ++mt) {
            #pragma unroll
            for (int nt = 0; nt < 6; ++nt)
                #pragma unroll
                for (int r = 0; r < 4; ++r)
                    tileT[(nt * 16 + l16) * 16 + quad * 4 + r] = (__bf16)(acc[mt][nt][r] + bq[nt]);
            int n0 = wv * 64 + mt * 16;
            #pragma unroll
            for (int it = 0; it < 3; ++it) {
                int qid = lane + 64 * it;           // < 192
                int col = qid >> 1, half = qid & 1;
                bf16x8 val = *(const bf16x8*)(tileT + col * 16 + half * 8);
                int cw = cloc + col;
                int h = cw >> 5, d = cw & 31;
                *(bf16x8*)(outp + (((size_t)b * HEADS + h) * HD + d) * NTOK + n0 + half * 8) = val;
            }
        }
    }
}

// ---------------- MFMA attention: in-register P via permuted-K rows ----------------
// K fragment rows loaded in permuted order kappa(kt,p)=8*(p>>2)+(p&3)+4*kt, so QK^T's
// output lands with lane (quad,l16) holding keys 8*quad..8*quad+7 for query l16 ==
// exactly the PV A-fragment. P never touches LDS; qt iterations fully independent.
// Ks swizzle G(key)=bit1|bit3<<1 keeps the permuted read 2-way (free) in banks.
// LDS = 16K (K) + 16K (V^T) = 32768 B. launch_bounds(256,4): 128-VGPR cap, NO spill
// (round-5's (256,5) forced VGPR=48 and spilled o/qf/bmv to scratch: WRITE 365MB).
__launch_bounds__(256, 4)
__global__ void attn_mfma(const __bf16* __restrict__ qg, const __bf16* __restrict__ kg,
                          const __bf16* __restrict__ vtg, const __bf16* __restrict__ bm,
                          __bf16* __restrict__ aout) {
    __shared__ __bf16 Ks[NTOK * 32];    // [key][dim], chunk c stores K[key][c ^ G(key)]
    __shared__ __bf16 VTs[HD * 256];    // [d][n],    chunk c stores vT[d][c ^ (d&7)]

    const int lin = blockIdx.x;                     // [0,1536)
    const int xcd = lin & 7, pos = lin >> 3;        // pos < 192
    const int g = xcd + (pos >> 2) * 8;             // (w,h) group [0,384)
    const int i4 = pos & 3;                         // batch group [0,4)
    const int h = g % 6, w = g / 6;
    const int b = i4 * 64 + w;
    const int bh = b * HEADS + h;

    const int t = threadIdx.x;
    const int wv = t >> 6, lane = t & 63;
    const int l16 = lane & 15, quad = lane >> 4;
    const int q0 = wv * 64;
    const size_t base = (size_t)bh * (NTOK * HD);

    #pragma unroll
    for (int it = 0; it < 4; ++it) {                // K: 1024 chunks, G-swizzled source
        int grp = it * 4 + wv;
        int cid = grp * 64 + lane;
        int row = cid >> 2, cc = cid & 3;
        int scc = cc ^ (((row >> 1) & 1) | (((row >> 3) & 1) << 1));
        gload_lds16(kg + base + row * HD + scc * 8, Ks + grp * 512);
    }
    #pragma unroll
    for (int it = 0; it < 4; ++it) {                // V^T: 1024 chunks, swizzled source
        int grp = it * 4 + wv;
        int cid = grp * 64 + lane;
        int row = cid >> 5, cc = cid & 31;
        int scc = cc ^ (row & 7);
        gload_lds16(vtg + base + row * NTOK + scc * 8, VTs + grp * 512);
    }
    __syncthreads();

    bf16x8 qf[4];
    #pragma unroll
    for (int qt = 0; qt < 4; ++qt)
        qf[qt] = *(const bf16x8*)(qg + base + (size_t)(q0 + qt * 16 + l16) * HD + quad * 8);

    f32x4 o[4][2];
    #pragma unroll
    for (int qt = 0; qt < 4; ++qt)
        #pragma unroll
        for (int dt = 0; dt < 2; ++dt)
            o[qt][dt] = (f32x4){0.f, 0.f, 0.f, 0.f};
    float rsum[4] = {};

    // bm: with the key permutation, lane (quad,l16) needs keys kb+8*quad..+8 -> ONE bf16x8
    const __bf16* bmq = bm + (size_t)(w * 6 + h) * 65536 + (size_t)(q0 + l16) * 256 + quad * 8;
    // permuted K-row index within the 32-key block, and its bank-fix read chunk
    const int kapb = 8 * (l16 >> 2) + (l16 & 3);    // kappa = kapb + 4*kt
    const int ck = quad ^ ((l16 >> 1) & 1) ^ (((l16 >> 2) & 1) << 1);
    const int xv = l16 & 7;                         // V read chunk XOR

    for (int c = 0; c < 8; ++c) {
        const int kb = c * 32;
        bf16x8 bmv[4];                               // 4 L2-resident loads, issued together;
        #pragma unroll                               // latency hidden by qt-chain ILP
        for (int qt = 0; qt < 4; ++qt)
            bmv[qt] = *(const bf16x8*)(bmq + qt * 4096 + kb);
        bf16x8 kf[2];
        #pragma unroll
        for (int kt = 0; kt < 2; ++kt)
            kf[kt] = *(const bf16x8*)(Ks + (kb + kapb + 4 * kt) * 32 + ck * 8);
        bf16x8 vf[2];
        #pragma unroll
        for (int dt = 0; dt < 2; ++dt) {
            int cv = (c * 4 + quad) ^ xv;
            vf[dt] = *(const bf16x8*)(VTs + (dt * 16 + l16) * 256 + cv * 8);
        }

        #pragma unroll
        for (int qt = 0; qt < 4; ++qt) {
            bf16x8 pf;
            #pragma unroll
            for (int kt = 0; kt < 2; ++kt) {
                f32x4 s = (f32x4){0.f, 0.f, 0.f, 0.f};
                s = __builtin_amdgcn_mfma_f32_16x16x32_bf16(kf[kt], qf[qt], s, 0, 0, 0);
                #pragma unroll
                for (int r = 0; r < 4; ++r) {
                    float p = __builtin_amdgcn_exp2f(s[r] + (float)bmv[qt][kt * 4 + r]);
                    rsum[qt] += p;
                    pf[kt * 4 + r] = (__bf16)p;
                }
            }
            #pragma unroll
            for (int dt = 0; dt < 2; ++dt)
                o[qt][dt] = __builtin_amdgcn_mfma_f32_16x16x32_bf16(pf, vf[dt], o[qt][dt], 0, 0, 0);
        }
    }

    // row-sum reciprocal broadcast via shfl (no LDS, no divergence)
    float rstot[4];
    #pragma unroll
    for (int qt = 0; qt < 4; ++qt) {
        float s = rsum[qt];
        s += __shfl_xor(s, 16);
        s += __shfl_xor(s, 32);
        rstot[qt] = 1.0f / s;
    }
    #pragma unroll
    for (int qt = 0; qt < 4; ++qt) {
        #pragma unroll
        for (int r = 0; r < 4; ++r) {
            float inv = __shfl(rstot[qt], (lane & 48) | (quad * 4 + r));
            int qrow = q0 + qt * 16 + quad * 4 + r;
            #pragma unroll
            for (int dt = 0; dt < 2; ++dt)
                aout[((size_t)b * NTOK + qrow) * DIMC + h * HD + dt * 16 + l16] =
                    (__bf16)(o[qt][dt][r] * inv);
        }
    }
}

// ---------------- proj GEMM via MFMA: (65536x192)x(192x192) + bias, fp32 out ----------------
__launch_bounds__(256, 2)
__global__ void proj_mfma(const __bf16* __restrict__ A, const __bf16* __restrict__ Wt,
                          const float* __restrict__ bias, float* __restrict__ out) {
    __shared__ __bf16 As[256 * 64];
    __shared__ __bf16 Bs[96 * 64];
    const int t = threadIdx.x;
    const int wv = t >> 6, lane = t & 63;
    const int l16 = lane & 15, quad = lane >> 4;

    const int lin = blockIdx.x + blockIdx.y * 2;    // [0,512)
    const int xcd = lin & 7, pos = lin >> 3;        // pos < 64
    const int bx = pos & 1;
    const int by = xcd + (pos >> 1) * 8;            // [0,256)

    const int m0 = by * 256;
    const int j0 = bx * 96;

    f32x4 acc[4][6];
    #pragma unroll
    for (int mt = 0; mt < 4; ++mt)
        #pragma unroll
        for (int nt = 0; nt < 6; ++nt)
            acc[mt][nt] = (f32x4){0.f, 0.f, 0.f, 0.f};

    for (int kit = 0; kit < 3; ++kit) {
        const int k0 = kit * 64;
        #pragma unroll
        for (int gi = 0; gi < 8; ++gi) {
            int g = wv * 8 + gi;
            int cid = g * 64 + lane;
            int row = cid >> 3, kcs = cid & 7;
            int kcg = kcs ^ (row & 7);
            gload_lds16(A + (size_t)(m0 + row) * DIMC + k0 + kcg * 8, As + g * 512);
        }
        #pragma unroll
        for (int gi = 0; gi < 3; ++gi) {
            int g = wv * 3 + gi;
            int cid = g * 64 + lane;
            int n = cid >> 3, kcs = cid & 7;
            int kcg = kcs ^ (n & 7);
            gload_lds16(Wt + (size_t)(j0 + n) * DIMC + k0 + kcg * 8, Bs + g * 512);
        }
        __syncthreads();
        #pragma unroll
        for (int kk = 0; kk < 2; ++kk) {
            bf16x8 af[4], bfr[6];
            #pragma unroll
            for (int mt = 0; mt < 4; ++mt) {
                int row = wv * 64 + mt * 16 + l16;
                int ch = (kk * 4 + quad) ^ (row & 7);
                af[mt] = *(const bf16x8*)(As + row * 64 + ch * 8);
            }
            #pragma unroll
            for (int nt = 0; nt < 6; ++nt) {
                int n = nt * 16 + l16;
                int ch = (kk * 4 + quad) ^ (n & 7);
                bfr[nt] = *(const bf16x8*)(Bs + n * 64 + ch * 8);
            }
            #pragma unroll
            for (int mt = 0; mt < 4; ++mt)
                #pragma unroll
                for (int nt = 0; nt < 6; ++nt)
                    acc[mt][nt] = __builtin_amdgcn_mfma_f32_16x16x32_bf16(af[mt], bfr[nt], acc[mt][nt], 0, 0, 0);
        }
        __syncthreads();
    }

    #pragma unroll
    for (int nt = 0; nt < 6; ++nt) {
        int colg = j0 + nt * 16 + l16;
        float bv = bias[colg];
        #pragma unroll
        for (int mt = 0; mt < 4; ++mt)
            #pragma unroll
            for (int r = 0; r < 4; ++r) {
                int token = m0 + wv * 64 + mt * 16 + quad * 4 + r;
                out[(size_t)token * DIMC + colg] = acc[mt][nt][r] + bv;
            }
    }
}

extern "C" void kernel_launch(void* const* d_in, const int* in_sizes, int n_in,
                              void* d_out, int out_size, void* d_ws, size_t ws_size,
                              hipStream_t stream) {
    const float* x          = (const float*)d_in[0];
    const float* mask       = (const float*)d_in[1];
    const float* qkv_w      = (const float*)d_in[2];
    const float* qkv_b      = (const float*)d_in[3];
    const float* proj_w     = (const float*)d_in[4];
    const float* proj_b     = (const float*)d_in[5];
    const float* bias_table = (const float*)d_in[6];
    const int*   rel_index  = (const int*)d_in[7];

    char* ws = (char*)d_ws;
    __bf16* xb    = (__bf16*)(ws);                  // 25,165,824 B (reused as aoutb)
    __bf16* q     = (__bf16*)(ws + 25165824);
    __bf16* k     = (__bf16*)(ws + 50331648);
    __bf16* vT    = (__bf16*)(ws + 75497472);       // V stored transposed [b,h,d,n]
    __bf16* biasb = (__bf16*)(ws + 100663296);      // 786,432 B (bf16 bias planes, *log2e)
    __bf16* wqt   = (__bf16*)(ws + 102236160);      // 221,184 B
    __bf16* wpt   = (__bf16*)(ws + 102457344);      // 73,728 B -> total ~102.5 MB
    __bf16* aoutb = xb;                             // xb dead after qkvbm
    __bf16* bm    = (__bf16*)d_out;                 // 50,331,648 B == out_size; d_out dead
                                                    // until proj_mfma overwrites it fully

    prep<<<8256, 256, 0, stream>>>(x, xb, qkv_w, wqt, proj_w, wpt, bias_table, rel_index, biasb);
    qkvbm<<<3584, 256, 0, stream>>>(xb, wqt, qkv_b, q, k, vT, mask, biasb, bm);
    attn_mfma<<<1536, 256, 0, stream>>>(q, k, vT, bm, aoutb);
    proj_mfma<<<dim3(2, 256), 256, 0, stream>>>(aoutb, wpt, proj_b, (float*)d_out);
}

// Round 7
// 206.500 us; speedup vs baseline: 2.2414x; 1.0252x over previous
//
#include <hip/hip_runtime.h>
#include <cstdint>
#include <math.h>

#define DIMC 192
#define NTOK 256
#define HEADS 6
#define HD 32
#define L2E 1.4426950408889634f

typedef __bf16 bf16x8 __attribute__((ext_vector_type(8)));
typedef __bf16 bf16x4 __attribute__((ext_vector_type(4)));
typedef float f32x4 __attribute__((ext_vector_type(4)));

__device__ __forceinline__ void gload_lds16(const __bf16* g, __bf16* l) {
    __builtin_amdgcn_global_load_lds((const __attribute__((address_space(1))) void*)g,
                                     (__attribute__((address_space(3))) void*)l, 16, 0, 0);
}

// ---------------- fused prep: cast_x | transcast(qkv_w) | transcast(proj_w) | biasb ----------------
// biasb is pre-multiplied by log2(e) so attention can use v_exp_f32 (base-2) directly.
__global__ void prep(const float* __restrict__ x, __bf16* __restrict__ xb,
                     const float* __restrict__ qkv_w, __bf16* __restrict__ wqt,
                     const float* __restrict__ proj_w, __bf16* __restrict__ wpt,
                     const float* __restrict__ table, const int* __restrict__ rel,
                     __bf16* __restrict__ biasb) {
    const int bid = blockIdx.x, t = threadIdx.x;
    if (bid < 6144) {                               // cast x -> bf16, one bf16x8/thread
        int i = bid * 256 + t;
        float4 a = ((const float4*)x)[i * 2];
        float4 b = ((const float4*)x)[i * 2 + 1];
        bf16x8 o = {(__bf16)a.x, (__bf16)a.y, (__bf16)a.z, (__bf16)a.w,
                    (__bf16)b.x, (__bf16)b.y, (__bf16)b.z, (__bf16)b.w};
        ((bf16x8*)xb)[i] = o;
    } else if (bid < 6576) {                        // wqt[n][k] = qkv_w[k][n]
        int i = (bid - 6144) * 256 + t;             // i < 576*192
        int n = i / DIMC, k = i - n * DIMC;
        wqt[i] = (__bf16)qkv_w[(size_t)k * 576 + n];
    } else if (bid < 6720) {                        // wpt[n][k] = proj_w[k][n]
        int i = (bid - 6576) * 256 + t;             // i < 192*192
        int n = i / DIMC, k = i - n * DIMC;
        wpt[i] = (__bf16)proj_w[(size_t)k * DIMC + n];
    } else {                                        // biasb[h][q][k] = bf16(table[rel]*log2e)
        int i = (bid - 6720) * 256 + t;             // i < 6*65536
        int h = i >> 16;
        int r = i & 65535;
        biasb[i] = (__bf16)(table[rel[r] * 6 + h] * L2E);
    }
}

// ---------------- fused QKV GEMM + bm build ----------------
// blocks [0,1536): MFMA GEMM (65536x192)x(192x576), XCD-aware remap.
//   q scaled by 1/sqrt(hd)*log2e; V written TRANSPOSED as vT[b,h,d,n] (attn consumes V^T only).
// blocks [1536,3584): bm[w][h][q][k] = bf16(mask*log2e + biasb)  (pure-BW, overlaps GEMM tail)
__launch_bounds__(256, 2)
__global__ void qkvbm(const __bf16* __restrict__ A, const __bf16* __restrict__ Wt,
                      const float* __restrict__ bias,
                      __bf16* __restrict__ qo, __bf16* __restrict__ ko, __bf16* __restrict__ vo,
                      const float* __restrict__ mask, const __bf16* __restrict__ biasb,
                      __bf16* __restrict__ bm) {
    __shared__ __bf16 As[256 * 64];    // 32KB
    __shared__ __bf16 Bs[96 * 64];     // 12KB
    const int t = threadIdx.x;
    const int lin = blockIdx.x;

    if (lin >= 1536) {                              // ---- bm build ----
        int i = (lin - 1536) * 256 + t;             // i < 64*8192
        int w = i >> 13, oct = i & 8191;
        float4 m0 = ((const float4*)mask)[(size_t)w * 16384 + oct * 2];
        float4 m1 = ((const float4*)mask)[(size_t)w * 16384 + oct * 2 + 1];
        #pragma unroll
        for (int h = 0; h < 6; ++h) {
            bf16x8 bb = ((const bf16x8*)biasb)[h * 8192 + oct];
            bf16x8 o = {(__bf16)(m0.x * L2E + (float)bb[0]), (__bf16)(m0.y * L2E + (float)bb[1]),
                        (__bf16)(m0.z * L2E + (float)bb[2]), (__bf16)(m0.w * L2E + (float)bb[3]),
                        (__bf16)(m1.x * L2E + (float)bb[4]), (__bf16)(m1.y * L2E + (float)bb[5]),
                        (__bf16)(m1.z * L2E + (float)bb[6]), (__bf16)(m1.w * L2E + (float)bb[7])};
            ((bf16x8*)bm)[(size_t)(w * 6 + h) * 8192 + oct] = o;
        }
        return;
    }

    const int wv = t >> 6, lane = t & 63;
    const int l16 = lane & 15, quad = lane >> 4;
    const int xcd = lin & 7, pos = lin >> 3;        // pos < 192
    const int bx = pos % 6;                         // column block (96 cols)
    const int by = xcd + (pos / 6) * 8;             // row block [0,256)
    const int m0 = by * 256;
    const int j0 = bx * 96;

    f32x4 acc[4][6];
    #pragma unroll
    for (int mt = 0; mt < 4; ++mt)
        #pragma unroll
        for (int nt = 0; nt < 6; ++nt)
            acc[mt][nt] = (f32x4){0.f, 0.f, 0.f, 0.f};

    for (int kit = 0; kit < 3; ++kit) {
        const int k0 = kit * 64;
        #pragma unroll
        for (int gi = 0; gi < 8; ++gi) {            // A: 2048 chunks, 32 groups
            int g = wv * 8 + gi;
            int cid = g * 64 + lane;
            int row = cid >> 3, kcs = cid & 7;
            int kcg = kcs ^ (row & 7);
            gload_lds16(A + (size_t)(m0 + row) * DIMC + k0 + kcg * 8, As + g * 512);
        }
        #pragma unroll
        for (int gi = 0; gi < 3; ++gi) {            // B: 768 chunks, 12 groups
            int g = wv * 3 + gi;
            int cid = g * 64 + lane;
            int n = cid >> 3, kcs = cid & 7;
            int kcg = kcs ^ (n & 7);
            gload_lds16(Wt + (size_t)(j0 + n) * DIMC + k0 + kcg * 8, Bs + g * 512);
        }
        __syncthreads();
        #pragma unroll
        for (int kk = 0; kk < 2; ++kk) {
            bf16x8 af[4], bfr[6];
            #pragma unroll
            for (int mt = 0; mt < 4; ++mt) {
                int row = wv * 64 + mt * 16 + l16;
                int ch = (kk * 4 + quad) ^ (row & 7);
                af[mt] = *(const bf16x8*)(As + row * 64 + ch * 8);
            }
            #pragma unroll
            for (int nt = 0; nt < 6; ++nt) {
                int n = nt * 16 + l16;
                int ch = (kk * 4 + quad) ^ (n & 7);
                bfr[nt] = *(const bf16x8*)(Bs + n * 64 + ch * 8);
            }
            #pragma unroll
            for (int mt = 0; mt < 4; ++mt)
                #pragma unroll
                for (int nt = 0; nt < 6; ++nt)
                    acc[mt][nt] = __builtin_amdgcn_mfma_f32_16x16x32_bf16(af[mt], bfr[nt], acc[mt][nt], 0, 0, 0);
        }
        __syncthreads();
    }

    const int which = bx >> 1;                      // 0=q, 1=k, 2=v
    __bf16* outp = which == 0 ? qo : (which == 1 ? ko : vo);
    const float sc = which == 0 ? (0.17677669529663687f * L2E) : 1.0f;
    float bq[6];
    #pragma unroll
    for (int nt = 0; nt < 6; ++nt) bq[nt] = bias[j0 + nt * 16 + l16];
    const int cloc = (bx & 1) * 96;                 // col within 192
    const int b = m0 >> 8;                          // batch (m0 is a multiple of 256)

    if (which != 2) {
        // q/k epilogue: re-tile via per-wave LDS, write bf16 [b,h,n,d] with 16B stores
        __bf16* tile = As + wv * 4096;              // per-wave 8KB, [16][104]
        const int TP = 104;
        #pragma unroll
        for (int mt = 0; mt < 4; ++mt) {
            #pragma unroll
            for (int nt = 0; nt < 6; ++nt)
                #pragma unroll
                for (int r = 0; r < 4; ++r)
                    tile[(quad * 4 + r) * TP + nt * 16 + l16] = (__bf16)((acc[mt][nt][r] + bq[nt]) * sc);
            int row = lane >> 2;
            #pragma unroll
            for (int it = 0; it < 3; ++it) {
                int c8 = (lane & 3) + it * 4;       // 12 16B-chunks per row
                bf16x8 val = *(const bf16x8*)(tile + row * TP + c8 * 8);
                int n = wv * 64 + mt * 16 + row;
                int cw = cloc + c8 * 8;
                int h = cw >> 5, d0 = cw & 31;
                *(bf16x8*)(outp + (((size_t)b * HEADS + h) * NTOK + n) * HD + d0) = val;
            }
        }
    } else {
        // v epilogue: transposed store vT[b,h,d,n] via per-wave LDS tileT[96][16]
        __bf16* tileT = As + wv * 4096;             // per-wave, 96*16 bf16 = 3KB
        #pragma unroll
        for (int mt = 0; mt < 4; ++mt) {
            #pragma unroll
            for (int nt = 0; nt < 6; ++nt)
                #pragma unroll
                for (int r = 0; r < 4; ++r)
                    tileT[(nt * 16 + l16) * 16 + quad * 4 + r] = (__bf16)(acc[mt][nt][r] + bq[nt]);
            int n0 = wv * 64 + mt * 16;
            #pragma unroll
            for (int it = 0; it < 3; ++it) {
                int qid = lane + 64 * it;           // < 192
                int col = qid >> 1, half = qid & 1;
                bf16x8 val = *(const bf16x8*)(tileT + col * 16 + half * 8);
                int cw = cloc + col;
                int h = cw >> 5, d = cw & 31;
                *(bf16x8*)(outp + (((size_t)b * HEADS + h) * HD + d) * NTOK + n0 + half * 8) = val;
            }
        }
    }
}

// ---------------- MFMA attention: 8-wave blocks, in-register P via permuted-K rows ----------------
// 512 threads / 8 waves per (b,h) block; each wave owns 32 q-rows. The 32KB K/V LDS stage
// is shared by 8 waves (2x the resident waves per block-slot vs the 4-wave version).
// K fragment rows loaded in permuted order kappa(kt,p)=8*(p>>2)+(p&3)+4*kt, so QK^T's
// output lands with lane (quad,l16) holding keys 8*quad..8*quad+7 for query l16 ==
// exactly the PV A-fragment. bm is folded into the QK MFMA's C-operand (D=A*B+C), so
// exp2 reads the MFMA output directly. P never touches LDS.
// launch_bounds(512,6): 85-VGPR cap (est. use ~70, no spill), 3 blocks/CU = 24 waves.
__launch_bounds__(512, 6)
__global__ void attn_mfma(const __bf16* __restrict__ qg, const __bf16* __restrict__ kg,
                          const __bf16* __restrict__ vtg, const __bf16* __restrict__ bm,
                          __bf16* __restrict__ aout) {
    __shared__ __bf16 Ks[NTOK * 32];    // [key][dim], chunk c stores K[key][c ^ G(key)]
    __shared__ __bf16 VTs[HD * 256];    // [d][n],    chunk c stores vT[d][c ^ (d&7)]

    const int lin = blockIdx.x;                     // [0,1536)
    const int xcd = lin & 7, pos = lin >> 3;        // pos < 192
    const int g = xcd + (pos >> 2) * 8;             // (w,h) group [0,384)
    const int i4 = pos & 3;                         // batch group [0,4)
    const int h = g % 6, w = g / 6;
    const int b = i4 * 64 + w;
    const int bh = b * HEADS + h;

    const int t = threadIdx.x;
    const int wv = t >> 6, lane = t & 63;           // wv in [0,8)
    const int l16 = lane & 15, quad = lane >> 4;
    const int q0 = wv * 32;
    const size_t base = (size_t)bh * (NTOK * HD);

    #pragma unroll
    for (int it = 0; it < 2; ++it) {                // K: 1024 chunks, G-swizzled source
        int grp = it * 8 + wv;
        int cid = grp * 64 + lane;
        int row = cid >> 2, cc = cid & 3;
        int scc = cc ^ (((row >> 1) & 1) | (((row >> 3) & 1) << 1));
        gload_lds16(kg + base + row * HD + scc * 8, Ks + grp * 512);
    }
    #pragma unroll
    for (int it = 0; it < 2; ++it) {                // V^T: 1024 chunks, swizzled source
        int grp = it * 8 + wv;
        int cid = grp * 64 + lane;
        int row = cid >> 5, cc = cid & 31;
        int scc = cc ^ (row & 7);
        gload_lds16(vtg + base + row * NTOK + scc * 8, VTs + grp * 512);
    }
    __syncthreads();

    bf16x8 qf[2];
    #pragma unroll
    for (int qt = 0; qt < 2; ++qt)
        qf[qt] = *(const bf16x8*)(qg + base + (size_t)(q0 + qt * 16 + l16) * HD + quad * 8);

    f32x4 o[2][2];
    #pragma unroll
    for (int qt = 0; qt < 2; ++qt)
        #pragma unroll
        for (int dt = 0; dt < 2; ++dt)
            o[qt][dt] = (f32x4){0.f, 0.f, 0.f, 0.f};
    float rsum[2] = {};

    // bm: with the key permutation, lane (quad,l16) needs keys kb+8*quad..+8 -> ONE bf16x8
    const __bf16* bmq = bm + (size_t)(w * 6 + h) * 65536 + (size_t)(q0 + l16) * 256 + quad * 8;
    // permuted K-row index within the 32-key block, and its bank-fix read chunk
    const int kapb = 8 * (l16 >> 2) + (l16 & 3);    // kappa = kapb + 4*kt
    const int ck = quad ^ ((l16 >> 1) & 1) ^ (((l16 >> 2) & 1) << 1);
    const int xv = l16 & 7;                         // V read chunk XOR

    for (int c = 0; c < 8; ++c) {
        const int kb = c * 32;
        bf16x8 bmv[2];                               // L2-resident, issued together
        #pragma unroll
        for (int qt = 0; qt < 2; ++qt)
            bmv[qt] = *(const bf16x8*)(bmq + qt * 4096 + kb);
        bf16x8 kf[2];
        #pragma unroll
        for (int kt = 0; kt < 2; ++kt)
            kf[kt] = *(const bf16x8*)(Ks + (kb + kapb + 4 * kt) * 32 + ck * 8);
        bf16x8 vf[2];
        #pragma unroll
        for (int dt = 0; dt < 2; ++dt) {
            int cv = (c * 4 + quad) ^ xv;
            vf[dt] = *(const bf16x8*)(VTs + (dt * 16 + l16) * 256 + cv * 8);
        }

        #pragma unroll
        for (int qt = 0; qt < 2; ++qt) {
            bf16x8 pf;
            #pragma unroll
            for (int kt = 0; kt < 2; ++kt) {
                f32x4 ci;                            // bm as MFMA C-in (off the exp chain)
                #pragma unroll
                for (int r = 0; r < 4; ++r)
                    ci[r] = (float)bmv[qt][kt * 4 + r];
                f32x4 s = __builtin_amdgcn_mfma_f32_16x16x32_bf16(kf[kt], qf[qt], ci, 0, 0, 0);
                #pragma unroll
                for (int r = 0; r < 4; ++r) {
                    float p = __builtin_amdgcn_exp2f(s[r]);
                    rsum[qt] += p;
                    pf[kt * 4 + r] = (__bf16)p;
                }
            }
            #pragma unroll
            for (int dt = 0; dt < 2; ++dt)
                o[qt][dt] = __builtin_amdgcn_mfma_f32_16x16x32_bf16(pf, vf[dt], o[qt][dt], 0, 0, 0);
        }
    }

    // row-sum reciprocal broadcast via shfl (no LDS, no divergence)
    float rstot[2];
    #pragma unroll
    for (int qt = 0; qt < 2; ++qt) {
        float s = rsum[qt];
        s += __shfl_xor(s, 16);
        s += __shfl_xor(s, 32);
        rstot[qt] = 1.0f / s;
    }
    #pragma unroll
    for (int qt = 0; qt < 2; ++qt) {
        #pragma unroll
        for (int r = 0; r < 4; ++r) {
            float inv = __shfl(rstot[qt], (lane & 48) | (quad * 4 + r));
            int qrow = q0 + qt * 16 + quad * 4 + r;
            #pragma unroll
            for (int dt = 0; dt < 2; ++dt)
                aout[((size_t)b * NTOK + qrow) * DIMC + h * HD + dt * 16 + l16] =
                    (__bf16)(o[qt][dt][r] * inv);
        }
    }
}

// ---------------- proj GEMM via MFMA: (65536x192)x(192x192) + bias, fp32 out ----------------
__launch_bounds__(256, 2)
__global__ void proj_mfma(const __bf16* __restrict__ A, const __bf16* __restrict__ Wt,
                          const float* __restrict__ bias, float* __restrict__ out) {
    __shared__ __bf16 As[256 * 64];
    __shared__ __bf16 Bs[96 * 64];
    const int t = threadIdx.x;
    const int wv = t >> 6, lane = t & 63;
    const int l16 = lane & 15, quad = lane >> 4;

    const int lin = blockIdx.x + blockIdx.y * 2;    // [0,512)
    const int xcd = lin & 7, pos = lin >> 3;        // pos < 64
    const int bx = pos & 1;
    const int by = xcd + (pos >> 1) * 8;            // [0,256)

    const int m0 = by * 256;
    const int j0 = bx * 96;

    f32x4 acc[4][6];
    #pragma unroll
    for (int mt = 0; mt < 4; ++mt)
        #pragma unroll
        for (int nt = 0; nt < 6; ++nt)
            acc[mt][nt] = (f32x4){0.f, 0.f, 0.f, 0.f};

    for (int kit = 0; kit < 3; ++kit) {
        const int k0 = kit * 64;
        #pragma unroll
        for (int gi = 0; gi < 8; ++gi) {
            int g = wv * 8 + gi;
            int cid = g * 64 + lane;
            int row = cid >> 3, kcs = cid & 7;
            int kcg = kcs ^ (row & 7);
            gload_lds16(A + (size_t)(m0 + row) * DIMC + k0 + kcg * 8, As + g * 512);
        }
        #pragma unroll
        for (int gi = 0; gi < 3; ++gi) {
            int g = wv * 3 + gi;
            int cid = g * 64 + lane;
            int n = cid >> 3, kcs = cid & 7;
            int kcg = kcs ^ (n & 7);
            gload_lds16(Wt + (size_t)(j0 + n) * DIMC + k0 + kcg * 8, Bs + g * 512);
        }
        __syncthreads();
        #pragma unroll
        for (int kk = 0; kk < 2; ++kk) {
            bf16x8 af[4], bfr[6];
            #pragma unroll
            for (int mt = 0; mt < 4; ++mt) {
                int row = wv * 64 + mt * 16 + l16;
                int ch = (kk * 4 + quad) ^ (row & 7);
                af[mt] = *(const bf16x8*)(As + row * 64 + ch * 8);
            }
            #pragma unroll
            for (int nt = 0; nt < 6; ++nt) {
                int n = nt * 16 + l16;
                int ch = (kk * 4 + quad) ^ (n & 7);
                bfr[nt] = *(const bf16x8*)(Bs + n * 64 + ch * 8);
            }
            #pragma unroll
            for (int mt = 0; mt < 4; ++mt)
                #pragma unroll
                for (int nt = 0; nt < 6; ++nt)
                    acc[mt][nt] = __builtin_amdgcn_mfma_f32_16x16x32_bf16(af[mt], bfr[nt], acc[mt][nt], 0, 0, 0);
        }
        __syncthreads();
    }

    #pragma unroll
    for (int nt = 0; nt < 6; ++nt) {
        int colg = j0 + nt * 16 + l16;
        float bv = bias[colg];
        #pragma unroll
        for (int mt = 0; mt < 4; ++mt)
            #pragma unroll
            for (int r = 0; r < 4; ++r) {
                int token = m0 + wv * 64 + mt * 16 + quad * 4 + r;
                out[(size_t)token * DIMC + colg] = acc[mt][nt][r] + bv;
            }
    }
}

extern "C" void kernel_launch(void* const* d_in, const int* in_sizes, int n_in,
                              void* d_out, int out_size, void* d_ws, size_t ws_size,
                              hipStream_t stream) {
    const float* x          = (const float*)d_in[0];
    const float* mask       = (const float*)d_in[1];
    const float* qkv_w      = (const float*)d_in[2];
    const float* qkv_b      = (const float*)d_in[3];
    const float* proj_w     = (const float*)d_in[4];
    const float* proj_b     = (const float*)d_in[5];
    const float* bias_table = (const float*)d_in[6];
    const int*   rel_index  = (const int*)d_in[7];

    char* ws = (char*)d_ws;
    __bf16* xb    = (__bf16*)(ws);                  // 25,165,824 B (reused as aoutb)
    __bf16* q     = (__bf16*)(ws + 25165824);
    __bf16* k     = (__bf16*)(ws + 50331648);
    __bf16* vT    = (__bf16*)(ws + 75497472);       // V stored transposed [b,h,d,n]
    __bf16* biasb = (__bf16*)(ws + 100663296);      // 786,432 B (bf16 bias planes, *log2e)
    __bf16* wqt   = (__bf16*)(ws + 102236160);      // 221,184 B
    __bf16* wpt   = (__bf16*)(ws + 102457344);      // 73,728 B -> total ~102.5 MB
    __bf16* aoutb = xb;                             // xb dead after qkvbm
    __bf16* bm    = (__bf16*)d_out;                 // 50,331,648 B == out_size; d_out dead
                                                    // until proj_mfma overwrites it fully

    prep<<<8256, 256, 0, stream>>>(x, xb, qkv_w, wqt, proj_w, wpt, bias_table, rel_index, biasb);
    qkvbm<<<3584, 256, 0, stream>>>(xb, wqt, qkv_b, q, k, vT, mask, biasb, bm);
    attn_mfma<<<1536, 512, 0, stream>>>(q, k, vT, bm, aoutb);
    proj_mfma<<<dim3(2, 256), 256, 0, stream>>>(aoutb, wpt, proj_b, (float*)d_out);
}